// Round 11
// baseline (158.790 us; speedup 1.0000x reference)
//
#include <hip/hip_runtime.h>
#include <hip/hip_bf16.h>

// GAT layer: N=4096, F_IN=128, F_OUT=64, HEADS=4.
// R22 (= R21 resubmitted after infra failure; R20 typo fixed): LDS-read pipe
// is the bottleneck (per block-chunk: 144 LDS reads ≈ 1700 cy of ~2100
// cy/chunk; VALU 720 and MFMA 80 fit under it). Half the reads were
// duplicates: rg-paired waves (same kg) read IDENTICAL B-fragments and
// ed/ed2. Remap: one wave per 32-col group (8 groups of the 256-col chunk),
// each wave computes BOTH 16-row halves (two af sets, two acc sets, shared
// B/ed reads). Block-chunk LDS reads 144 -> 80. Cost: +20 acc VGPRs (~100
// total, under the (512,4)=128 budget -> no spill). Staging
// (global_load_lds DMA), barriers, VALU, MFMA totals unchanged.
// Kernels: pack_bits -> gat_prep -> gat_main (fused) -> gat_fin (tiny).

#define NN 4096
#define FIN 128
#define FOUT 64
#define NH 4

typedef __attribute__((ext_vector_type(8))) short bf16x8;
typedef __attribute__((ext_vector_type(4))) float f32x4;
typedef __attribute__((ext_vector_type(4))) unsigned int u32x4;

__device__ __forceinline__ unsigned short f32_bf16(float f) {
    unsigned u = __builtin_bit_cast(unsigned, f);
    u += 0x7fffu + ((u >> 16) & 1u);          // round-to-nearest-even
    return (unsigned short)(u >> 16);
}

__device__ __forceinline__ void gload16(const void* g, void* l) {
    __builtin_amdgcn_global_load_lds(
        (const __attribute__((address_space(1))) unsigned*)g,
        (__attribute__((address_space(3))) unsigned*)l, 16, 0, 0);
}

// ---------------- Kernel 0: pack A (int32 0/1) into bitmask ----------------
__global__ __launch_bounds__(256) void pack_bits(
    const int* __restrict__ A, unsigned long long* __restrict__ Abits)
{
    const int row  = blockIdx.x;
    const int lane = threadIdx.x & 63;
    const int wv   = threadIdx.x >> 6;
    const int* arow = A + (size_t)row * NN;
    #pragma unroll 4
    for (int c = 0; c < 16; ++c) {
        const int col = c * 256 + wv * 64 + lane;
        unsigned long long m = __ballot(__builtin_nontemporal_load(&arow[col]) > 0);
        if (lane == 0) Abits[(size_t)row * 64 + c * 4 + wv] = m;
    }
}

// ---------------- Kernel 1: prep ----------------
__global__ __launch_bounds__(256) void gat_prep(
    const float* __restrict__ X, const float* __restrict__ W,
    const float* __restrict__ b, const float* __restrict__ att,
    unsigned short* __restrict__ HbfT, float* __restrict__ Hrow,
    float* __restrict__ s_out, float* __restrict__ d_out,
    float* __restrict__ es_g, float* __restrict__ es2_g,
    float* __restrict__ ed_g, float* __restrict__ ed2_g)
{
    const int rb = blockIdx.x;           // 0..127
    const int h  = blockIdx.y;           // 0..3
    const int n0 = rb * 32;
    const int t  = threadIdx.x;          // 0..255

    __shared__ float Xl[32][132];
    __shared__ float Wt[128][68];

    for (int g = t; g < 32 * 32; g += 256) {
        int row = g >> 5, c4 = g & 31;
        float4 v = *(const float4*)&X[(size_t)(n0 + row) * FIN + c4 * 4];
        *(float4*)&Xl[row][c4 * 4] = v;
    }
    for (int g = t; g < 64 * 32; g += 256) {
        int o = g >> 5, c4 = g & 31;
        float4 v = *(const float4*)&W[((size_t)h * FOUT + o) * FIN + c4 * 4];
        Wt[c4 * 4 + 0][o] = v.x; Wt[c4 * 4 + 1][o] = v.y;
        Wt[c4 * 4 + 2][o] = v.z; Wt[c4 * 4 + 3][o] = v.w;
    }
    __syncthreads();

    const int rg = t >> 4;               // rows rg*2 .. rg*2+1
    const int og = t & 15;               // cols og*4 .. og*4+3
    float acc[2][4] = {};

    #pragma unroll 4
    for (int f4 = 0; f4 < 32; ++f4) {
        float xv[2][4], wv[4][4];
        #pragma unroll
        for (int i = 0; i < 2; ++i) {
            float4 tmp = *(const float4*)&Xl[rg * 2 + i][f4 * 4];
            xv[i][0] = tmp.x; xv[i][1] = tmp.y; xv[i][2] = tmp.z; xv[i][3] = tmp.w;
        }
        #pragma unroll
        for (int k = 0; k < 4; ++k) {
            float4 tmp = *(const float4*)&Wt[f4 * 4 + k][og * 4];
            wv[k][0] = tmp.x; wv[k][1] = tmp.y; wv[k][2] = tmp.z; wv[k][3] = tmp.w;
        }
        #pragma unroll
        for (int i = 0; i < 2; ++i)
            #pragma unroll
            for (int k = 0; k < 4; ++k)
                #pragma unroll
                for (int jj = 0; jj < 4; ++jj)
                    acc[i][jj] = fmaf(xv[i][k], wv[k][jj], acc[i][jj]);
    }

    float bb[4], as_[4], ad_[4];
    #pragma unroll
    for (int jj = 0; jj < 4; ++jj) {
        bb[jj]  = b[h * FOUT + og * 4 + jj];
        as_[jj] = att[h * 2 * FOUT + og * 4 + jj];
        ad_[jj] = att[h * 2 * FOUT + FOUT + og * 4 + jj];
    }
    #pragma unroll
    for (int i = 0; i < 2; ++i)
        #pragma unroll
        for (int jj = 0; jj < 4; ++jj)
            acc[i][jj] += bb[jj];

    float sp[2] = {0.f, 0.f}, dp[2] = {0.f, 0.f};
    #pragma unroll
    for (int i = 0; i < 2; ++i)
        #pragma unroll
        for (int jj = 0; jj < 4; ++jj) {
            sp[i] = fmaf(acc[i][jj], as_[jj], sp[i]);
            dp[i] = fmaf(acc[i][jj], ad_[jj], dp[i]);
        }
    #pragma unroll
    for (int off = 1; off < 16; off <<= 1) {
        #pragma unroll
        for (int i = 0; i < 2; ++i) {
            sp[i] += __shfl_xor(sp[i], off);
            dp[i] += __shfl_xor(dp[i], off);
        }
    }
    if (og == 0) {
        #pragma unroll
        for (int i = 0; i < 2; ++i) {
            int nn = n0 + rg * 2 + i;
            s_out[h * NN + nn]  = sp[i];
            d_out[h * NN + nn]  = dp[i];
            es_g [h * NN + nn]  = __expf(sp[i]);
            es2_g[h * NN + nn]  = __expf(0.01f * sp[i]);
            ed_g [h * NN + nn]  = __expf(dp[i]);
            ed2_g[h * NN + nn]  = __expf(0.01f * dp[i]);
        }
    }

    #pragma unroll
    for (int i = 0; i < 2; ++i) {
        float4 v = make_float4(acc[i][0], acc[i][1], acc[i][2], acc[i][3]);
        *(float4*)&Hrow[((size_t)h * NN + n0 + rg * 2 + i) * FOUT + og * 4] = v;
    }
    #pragma unroll
    for (int jj = 0; jj < 4; ++jj) {
        int o = og * 4 + jj;
        ushort2 p;
        p.x = f32_bf16(acc[0][jj]);
        p.y = f32_bf16(acc[1][jj]);
        *(ushort2*)&HbfT[((size_t)h * FOUT + o) * NN + n0 + rg * 2] = p;
    }
}

// ---------------- Kernel 2: fused masked softmax-aggregate ------------------
// Grid 512 x 512thr. id -> h = id&3, tile = id>>2 (32 rows). 8 waves, wave w
// owns 32-col group w of each 256-col chunk (16 chunks) and computes BOTH
// 16-row halves (afA rows 0..15, afB rows 16..31) sharing one set of
// B-fragment and ed/ed2 LDS reads. All staging via global_load_lds DMA.
// Epilogue: 8-way group reduction in LDS (aliases H), fused normalize+store.
struct SMem {
    union {
        __align__(16) unsigned short H[2][64][256];  // 64 KB dbuf
        struct {
            float red[7][32][68];                    // 60.9 KB (pad 68)
            float redl[7][32];
        } fin;
    };
    unsigned bits[2][32][8];                         // 2 KB (gload: linear)
    float ed [2][256];                               // 2 KB
    float ed2[2][256];                               // 2 KB
};

__global__ __launch_bounds__(512, 4) void gat_main(
    const unsigned* __restrict__ Abits, const unsigned short* __restrict__ HbfT,
    const float* __restrict__ s_g, const float* __restrict__ d_g,
    const float* __restrict__ es_g, const float* __restrict__ es2_g,
    const float* __restrict__ ed_g, const float* __restrict__ ed2_g,
    const float* __restrict__ Hrow, float* __restrict__ outH)
{
    const int id   = blockIdx.x;         // 0..511
    const int h    = id & 3;
    const int tile = id >> 2;            // 0..127
    const int n0   = tile * 32;
    const int tid  = threadIdx.x;        // 0..511
    const int w    = tid >> 6;           // wave 0..7 = column group
    const int lane = tid & 63;
    const int r    = lane & 15;          // A row within 16-row half / C col
    const int q    = lane >> 4;          // quad
    const int qs   = q * 8;

    __shared__ SMem sm;                  // ~70 KB -> 2 blocks/CU

    // es for both row-halves this lane's A-row covers
    const float es_a  = es_g [h * NN + n0 + r];
    const float es2_a = es2_g[h * NN + n0 + r];
    const float es_b  = es_g [h * NN + n0 + 16 + r];
    const float es2_b = es2_g[h * NN + n0 + 16 + r];

    // swizzled 16B-block index for B-fragment reads (constant per thread)
    const int cb   = w * 4 + q;                        // 0..31
    const int sblk = ((cb & 15) ^ r) | (cb & 16);

    // ---- gload_lds sources (H pre-swizzled; bits/ed/ed2 linear) ----
    // H: wave w stages rows [8w, 8w+8) via 4 DMA instrs, 2 rows each.
    const int blk = lane & 31;
    const unsigned short* gH[4];
    #pragma unroll
    for (int i = 0; i < 4; ++i) {
        const int row = 8 * w + 2 * i + (lane >> 5);
        const int gb  = ((blk & 15) ^ (row & 15)) | (blk & 16);
        gH[i] = HbfT + ((size_t)(h * FOUT) + row) * NN + gb * 8;
    }
    // bits (wave 0): 32 rows x 8 u32 per chunk = 1 KB, lane -> (row, 4 words)
    const unsigned* gBits = Abits + (size_t)(n0 + (lane >> 1)) * 128 + (lane & 1) * 4;
    // ed / ed2 (waves 1 / 2): 256 floats per chunk = 1 KB
    const float* gEd  = ed_g  + (size_t)h * NN + lane * 4;
    const float* gEd2 = ed2_g + (size_t)h * NN + lane * 4;

    bf16x8 ones;
    #pragma unroll
    for (int i = 0; i < 8; ++i) ones[i] = (short)0x3F80;   // bf16 1.0

    f32x4 a0 = {0,0,0,0}, a1 = {0,0,0,0}, a2 = {0,0,0,0},
          a3 = {0,0,0,0}, al = {0,0,0,0};
    f32x4 b0a = {0,0,0,0}, b1a = {0,0,0,0}, b2a = {0,0,0,0},
          b3a = {0,0,0,0}, bla = {0,0,0,0};

    // ---- prologue: stage chunk 0 into buffer 0 (async DMA) ----
    {
        unsigned short* hw = &sm.H[0][8 * w][0];
        gload16(gH[0], hw);
        gload16(gH[1], hw +  512);
        gload16(gH[2], hw + 1024);
        gload16(gH[3], hw + 1536);
        if      (w == 0) gload16(gBits, &sm.bits[0][0][0]);
        else if (w == 1) gload16(gEd,   &sm.ed [0][0]);
        else if (w == 2) gload16(gEd2,  &sm.ed2[0][0]);
    }
    __syncthreads();                     // vmcnt(0) drain + barrier

    #pragma unroll 2
    for (int ch = 0; ch < 16; ++ch) {
        const int buf = ch & 1;

        // issue next chunk's DMA (lands during this chunk's compute)
        if (ch < 15) {
            const int nb   = buf ^ 1;
            const int coff = (ch + 1) * 256;
            unsigned short* hw = &sm.H[nb][8 * w][0];
            gload16(gH[0] + coff, hw);
            gload16(gH[1] + coff, hw +  512);
            gload16(gH[2] + coff, hw + 1024);
            gload16(gH[3] + coff, hw + 1536);
            if      (w == 0) gload16(gBits + (ch + 1) * 8, &sm.bits[nb][0][0]);
            else if (w == 1) gload16(gEd  + coff, &sm.ed [nb][0]);
            else if (w == 2) gload16(gEd2 + coff, &sm.ed2[nb][0]);
        }

        // ---- shared per-group inputs: ed/ed2 (read ONCE for both halves) ----
        const float4 e0 = *(const float4*)&sm.ed [buf][w * 32 + qs];
        const float4 e1 = *(const float4*)&sm.ed [buf][w * 32 + qs + 4];
        const float4 g0 = *(const float4*)&sm.ed2[buf][w * 32 + qs];
        const float4 g1 = *(const float4*)&sm.ed2[buf][w * 32 + qs + 4];
        const float edv [8] = {e0.x, e0.y, e0.z, e0.w, e1.x, e1.y, e1.z, e1.w};
        const float ed2v[8] = {g0.x, g0.y, g0.z, g0.w, g1.x, g1.y, g1.z, g1.w};
        const unsigned bits8a = sm.bits[buf][r     ][w] >> qs;
        const unsigned bits8b = sm.bits[buf][r + 16][w] >> qs;

        // ---- B fragments (read ONCE, feed both halves) ----
        const bf16x8 f0 = *(const bf16x8*)&sm.H[buf][r     ][sblk * 8];
        const bf16x8 f1 = *(const bf16x8*)&sm.H[buf][r + 16][sblk * 8];
        const bf16x8 f2 = *(const bf16x8*)&sm.H[buf][r + 32][sblk * 8];
        const bf16x8 f3 = *(const bf16x8*)&sm.H[buf][r + 48][sblk * 8];

        // ---- af for both row-halves ----
        u32x4 afuA, afuB;
        #pragma unroll
        for (int p = 0; p < 4; ++p) {
            const int j0 = 2 * p, j1 = 2 * p + 1;
            float wa = (bits8a & (1u << j0))
                     ? fmaxf(es_a * edv[j0], es2_a * ed2v[j0]) : 0.0f;
            float wb = (bits8a & (1u << j1))
                     ? fmaxf(es_a * edv[j1], es2_a * ed2v[j1]) : 0.0f;
            __hip_bfloat162 pk = __float22bfloat162_rn(make_float2(wa, wb));
            unsigned u;
            __builtin_memcpy(&u, &pk, sizeof(u));   // v_cvt_pk path
            afuA[p] = u;
            float wc = (bits8b & (1u << j0))
                     ? fmaxf(es_b * edv[j0], es2_b * ed2v[j0]) : 0.0f;
            float wd = (bits8b & (1u << j1))
                     ? fmaxf(es_b * edv[j1], es2_b * ed2v[j1]) : 0.0f;
            __hip_bfloat162 pk2 = __float22bfloat162_rn(make_float2(wc, wd));
            __builtin_memcpy(&u, &pk2, sizeof(u));
            afuB[p] = u;
        }
        const bf16x8 afA = __builtin_bit_cast(bf16x8, afuA);
        const bf16x8 afB = __builtin_bit_cast(bf16x8, afuB);

        a0  = __builtin_amdgcn_mfma_f32_16x16x32_bf16(afA, f0,   a0,  0, 0, 0);
        a1  = __builtin_amdgcn_mfma_f32_16x16x32_bf16(afA, f1,   a1,  0, 0, 0);
        a2  = __builtin_amdgcn_mfma_f32_16x16x32_bf16(afA, f2,   a2,  0, 0, 0);
        a3  = __builtin_amdgcn_mfma_f32_16x16x32_bf16(afA, f3,   a3,  0, 0, 0);
        al  = __builtin_amdgcn_mfma_f32_16x16x32_bf16(afA, ones, al,  0, 0, 0);
        b0a = __builtin_amdgcn_mfma_f32_16x16x32_bf16(afB, f0,   b0a, 0, 0, 0);
        b1a = __builtin_amdgcn_mfma_f32_16x16x32_bf16(afB, f1,   b1a, 0, 0, 0);
        b2a = __builtin_amdgcn_mfma_f32_16x16x32_bf16(afB, f2,   b2a, 0, 0, 0);
        b3a = __builtin_amdgcn_mfma_f32_16x16x32_bf16(afB, f3,   b3a, 0, 0, 0);
        bla = __builtin_amdgcn_mfma_f32_16x16x32_bf16(afB, ones, bla, 0, 0, 0);

        __syncthreads();                 // drains next-chunk DMA + barrier
    }

    // ---- group reduction: waves 1..7 dump to LDS, wave 0 accumulates ----
    // (sm.fin aliases sm.H — all stage reads completed before last barrier)
    if (w > 0) {
        #pragma unroll
        for (int reg = 0; reg < 4; ++reg) {
            const int rr = q * 4 + reg;
            sm.fin.red[w - 1][rr][ 0 + r] = a0[reg];
            sm.fin.red[w - 1][rr][16 + r] = a1[reg];
            sm.fin.red[w - 1][rr][32 + r] = a2[reg];
            sm.fin.red[w - 1][rr][48 + r] = a3[reg];
            sm.fin.red[w - 1][16 + rr][ 0 + r] = b0a[reg];
            sm.fin.red[w - 1][16 + rr][16 + r] = b1a[reg];
            sm.fin.red[w - 1][16 + rr][32 + r] = b2a[reg];
            sm.fin.red[w - 1][16 + rr][48 + r] = b3a[reg];
        }
        if (r == 0) {
            #pragma unroll
            for (int reg = 0; reg < 4; ++reg) {
                sm.fin.redl[w - 1][q * 4 + reg]      = al[reg];
                sm.fin.redl[w - 1][16 + q * 4 + reg] = bla[reg];
            }
        }
    }
    __syncthreads();
    if (w == 0) {
        #pragma unroll
        for (int kk = 0; kk < 7; ++kk) {
            #pragma unroll
            for (int reg = 0; reg < 4; ++reg) {
                const int rr = q * 4 + reg;
                a0[reg]  += sm.fin.red[kk][rr][ 0 + r];
                a1[reg]  += sm.fin.red[kk][rr][16 + r];
                a2[reg]  += sm.fin.red[kk][rr][32 + r];
                a3[reg]  += sm.fin.red[kk][rr][48 + r];
                al[reg]  += sm.fin.redl[kk][rr];
                b0a[reg] += sm.fin.red[kk][16 + rr][ 0 + r];
                b1a[reg] += sm.fin.red[kk][16 + rr][16 + r];
                b2a[reg] += sm.fin.red[kk][16 + rr][32 + r];
                b3a[reg] += sm.fin.red[kk][16 + rr][48 + r];
                bla[reg] += sm.fin.redl[kk][16 + rr];
            }
        }
        // ---- fused normalize + diagonal + store per-head output ----
        #pragma unroll
        for (int reg = 0; reg < 4; ++reg) {
            const int rr = q * 4 + reg;
            {
                const int nn2 = n0 + rr;
                const float tt = s_g[h * NN + nn2] + d_g[h * NN + nn2];
                const float wd = __expf(fmaxf(tt, 0.01f * tt));
                const float inv = 0.25f / (al[reg] + wd);
                const float* hr = &Hrow[((size_t)h * NN + nn2) * FOUT];
                float*       ob = &outH[((size_t)h * NN + nn2) * FOUT];
                ob[ 0 + r] = (a0[reg] + wd * hr[ 0 + r]) * inv;
                ob[16 + r] = (a1[reg] + wd * hr[16 + r]) * inv;
                ob[32 + r] = (a2[reg] + wd * hr[32 + r]) * inv;
                ob[48 + r] = (a3[reg] + wd * hr[48 + r]) * inv;
            }
            {
                const int nn2 = n0 + 16 + rr;
                const float tt = s_g[h * NN + nn2] + d_g[h * NN + nn2];
                const float wd = __expf(fmaxf(tt, 0.01f * tt));
                const float inv = 0.25f / (bla[reg] + wd);
                const float* hr = &Hrow[((size_t)h * NN + nn2) * FOUT];
                float*       ob = &outH[((size_t)h * NN + nn2) * FOUT];
                ob[ 0 + r] = (b0a[reg] + wd * hr[ 0 + r]) * inv;
                ob[16 + r] = (b1a[reg] + wd * hr[16 + r]) * inv;
                ob[32 + r] = (b2a[reg] + wd * hr[32 + r]) * inv;
                ob[48 + r] = (b3a[reg] + wd * hr[48 + r]) * inv;
            }
        }
    }
}

// ---------------- Kernel 3: tiny finalize — sum 4 heads ----------------
__global__ __launch_bounds__(256) void gat_fin(
    const float* __restrict__ outH, float* __restrict__ out)
{
    const int i = blockIdx.x * 256 + threadIdx.x;    // 0..65535 float4s
    const f32x4* p = (const f32x4*)outH;
    f32x4 v0 = __builtin_nontemporal_load(p + i);
    f32x4 v1 = __builtin_nontemporal_load(p + i +  65536);
    f32x4 v2 = __builtin_nontemporal_load(p + i + 131072);
    f32x4 v3 = __builtin_nontemporal_load(p + i + 196608);
    f32x4 s = (v0 + v1) + (v2 + v3);
    *((f32x4*)out + i) = s;
}

extern "C" void kernel_launch(void* const* d_in, const int* in_sizes, int n_in,
                              void* d_out, int out_size, void* d_ws, size_t ws_size,
                              hipStream_t stream) {
    const float* X   = (const float*)d_in[0];
    const int*   A   = (const int*)  d_in[1];
    const float* W   = (const float*)d_in[2];
    const float* b   = (const float*)d_in[3];
    const float* att = (const float*)d_in[4];
    float* out = (float*)d_out;

    char* ws = (char*)d_ws;
    unsigned short* HbfT = (unsigned short*)ws;                    // 2 MB
    size_t off = (size_t)NH * FOUT * NN * 2;
    float* s_buf   = (float*)(ws + off);  off += (size_t)NH * NN * 4;
    float* d_buf   = (float*)(ws + off);  off += (size_t)NH * NN * 4;
    float* es_buf  = (float*)(ws + off);  off += (size_t)NH * NN * 4;
    float* es2_buf = (float*)(ws + off);  off += (size_t)NH * NN * 4;
    float* ed_buf  = (float*)(ws + off);  off += (size_t)NH * NN * 4;
    float* ed2_buf = (float*)(ws + off);  off += (size_t)NH * NN * 4;
    unsigned long long* Abits = (unsigned long long*)(ws + off);
    off += (size_t)NN * 64 * 8;                                         // 2 MB
    float* Hrow   = (float*)(ws + off);
    off += (size_t)NH * NN * FOUT * 4;                                  // 4 MB
    float* outH   = (float*)(ws + off);
    off += (size_t)NH * NN * FOUT * 4;                                  // 4 MB

    pack_bits<<<NN, 256, 0, stream>>>(A, Abits);
    gat_prep<<<dim3(128, 4), 256, 0, stream>>>(X, W, b, att, HbfT, Hrow,
                                               s_buf, d_buf,
                                               es_buf, es2_buf, ed_buf, ed2_buf);
    gat_main<<<512, 512, 0, stream>>>((const unsigned*)Abits, HbfT,
                                      s_buf, d_buf,
                                      es_buf, es2_buf, ed_buf, ed2_buf,
                                      Hrow, outH);
    gat_fin<<<256, 256, 0, stream>>>(outH, out);
}